// Round 1
// baseline (306.938 us; speedup 1.0000x reference)
//
#include <hip/hip_runtime.h>
#include <cstdint>
#include <cstddef>

// Problem constants
//   x[1024,256] f32, W1[1024,256] f32, b1[1024], W2[32896,1024] f32, b2[32896]
//   h = softplus(x@W1^T + b1)          [1024,1024]  (kept bf16 in ws)
//   elements = h@W2^T + b2             first TRI=32640 cols used
//   out[b,i,j] = elements[b, i(i-1)/2+j] for i>j; out[b,j,i] = -that; diag 0
#define TRI 32640

using u32   = unsigned int;
using u16   = unsigned short;
using f32x4 = __attribute__((ext_vector_type(4))) float;
using u32x4 = __attribute__((ext_vector_type(4))) u32;
using bf16x8 = __attribute__((ext_vector_type(8))) short;   // 8 bf16 (guide §3)

__device__ __forceinline__ void gload_lds16(const void* g, void* l) {
  // async global->LDS, 16B/lane; LDS dest = wave-uniform base + lane*16
  __builtin_amdgcn_global_load_lds(
      (const __attribute__((address_space(1))) void*)g,
      (__attribute__((address_space(3))) void*)l, 16, 0, 0);
}

// truncating f32 pair -> packed bf16x2 (compiler can fuse to v_perm_b32)
__device__ __forceinline__ u32 pack2bf(float a, float b) {
  u32 ua = __builtin_bit_cast(u32, a);
  u32 ub = __builtin_bit_cast(u32, b);
  return (ub & 0xffff0000u) | (ua >> 16);
}

__device__ __forceinline__ u16 f2bf_rn(float f) {  // round-to-nearest-even
  u32 u = __builtin_bit_cast(u32, f);
  u += 0x7fffu + ((u >> 16) & 1u);
  return (u16)(u >> 16);
}

// ---------------------------------------------------------------------------
// K1: h = softplus(x @ W1^T + b1), bf16 out.  M=N=1024, K=256. 64 blocks.
// m97 structure: 128x128 tile, BK=32, 4 waves, 4x4 16x16 frags/wave.
// Both operands f32 -> staged f32 in LDS, packed to bf16 at frag load.
// ---------------------------------------------------------------------------
__global__ __launch_bounds__(256)
void k1_gemm_softplus(const float* __restrict__ x, const float* __restrict__ W1,
                      const float* __restrict__ b1, u16* __restrict__ h)
{
  __shared__ float ldsA[128*32];   // 16 KB
  __shared__ float ldsB[128*32];   // 16 KB
  const int tid = threadIdx.x, lane = tid & 63, wave = tid >> 6;
  const int wm = wave >> 1, wn = wave & 1;
  const int brow = (blockIdx.x & 7) * 128, bcol = (blockIdx.x >> 3) * 128;

  // staging: 4 issues/operand; issue q covers rows q*32 + wave*8 + lane/8
  const int s_row = wave*8 + (lane >> 3);
  const int s_col = (lane & 7) * 4;                 // 4 f32 = 16B
  const float* gA = x  + (brow + s_row)*256 + s_col;
  const float* gB = W1 + (bcol + s_row)*256 + s_col;
  float* lA = &ldsA[wave*256];                      // +q*1024 elems (uniform/wave)
  float* lB = &ldsB[wave*256];

  const int fr = lane & 15, fk = (lane >> 4) * 8;
  const float* rdA = &ldsA[(wm*64 + fr)*32 + fk];
  const float* rdB = &ldsB[(wn*64 + fr)*32 + fk];

  f32x4 acc[4][4] = {};
  for (int kt = 0; kt < 8; ++kt) {
    __syncthreads();
#pragma unroll
    for (int q = 0; q < 4; ++q) {
      gload_lds16(gA + q*32*256 + kt*32, lA + q*1024);
      gload_lds16(gB + q*32*256 + kt*32, lB + q*1024);
    }
    __syncthreads();
    bf16x8 af[4], bfv[4];
#pragma unroll
    for (int m = 0; m < 4; ++m) {
      f32x4 lo = *(const f32x4*)(rdA + m*512);
      f32x4 hi = *(const f32x4*)(rdA + m*512 + 4);
      u32x4 p = { pack2bf(lo.x,lo.y), pack2bf(lo.z,lo.w),
                  pack2bf(hi.x,hi.y), pack2bf(hi.z,hi.w) };
      af[m] = __builtin_bit_cast(bf16x8, p);
    }
#pragma unroll
    for (int n = 0; n < 4; ++n) {
      f32x4 lo = *(const f32x4*)(rdB + n*512);
      f32x4 hi = *(const f32x4*)(rdB + n*512 + 4);
      u32x4 p = { pack2bf(lo.x,lo.y), pack2bf(lo.z,lo.w),
                  pack2bf(hi.x,hi.y), pack2bf(hi.z,hi.w) };
      bfv[n] = __builtin_bit_cast(bf16x8, p);
    }
#pragma unroll
    for (int m = 0; m < 4; ++m)
#pragma unroll
      for (int n = 0; n < 4; ++n)
        acc[m][n] = __builtin_amdgcn_mfma_f32_16x16x32_bf16(af[m], bfv[n], acc[m][n], 0,0,0);
  }
  // epilogue: + b1, softplus, store bf16.  C/D: col=lane&15, row=(lane>>4)*4+r
#pragma unroll
  for (int n = 0; n < 4; ++n) {
    const int col = bcol + wn*64 + n*16 + fr;
    const float bias = b1[col];
#pragma unroll
    for (int m = 0; m < 4; ++m) {
      const int row0 = brow + wm*64 + m*16 + (lane >> 4)*4;
#pragma unroll
      for (int r = 0; r < 4; ++r) {
        float z = acc[m][n][r] + bias;
        float sp = fmaxf(z, 0.f) + log1pf(expf(-fabsf(z)));   // stable softplus
        h[(row0 + r)*1024 + col] = f2bf_rn(sp);
      }
    }
  }
}

// ---------------------------------------------------------------------------
// K2: elements = h @ W2^T (+b2), scattered to strict lower triangle of out.
// M=1024 (batch), N=32640 (tri index), K=1024. 255x8 = 2040 blocks.
// A (h) bf16 via gload_lds; B (W2) f32 via gload_lds, packed at frag load.
// Forward write only (coalesced along j); mirror handled by K3.
// ---------------------------------------------------------------------------
__global__ __launch_bounds__(256)
void k2_gemm_scatter(const u16* __restrict__ h, const float* __restrict__ W2,
                     const float* __restrict__ b2, float* __restrict__ out)
{
  __shared__ u16   ldsA[128*32];   // 8 KB bf16
  __shared__ float ldsB[128*32];   // 16 KB f32
  const int tid = threadIdx.x, lane = tid & 63, wave = tid >> 6;
  const int wm = wave >> 1, wn = wave & 1;

  // XCD-bijective swizzle (2040 % 8 == 0): XCD k gets contiguous logical range;
  // logical L = tt*8 + mb so 8 blocks sharing a W2 panel land on one XCD.
  const int bid = blockIdx.x;
  const int L  = (bid & 7) * 255 + (bid >> 3);
  const int t0 = (L >> 3) * 128;          // t-tile base (0..32512)
  const int brow = (L & 7) * 128;         // batch-tile base

  // A staging: 2 issues; issue q covers rows q*64 + wave*16 + lane/4
  const int a_row = wave*16 + (lane >> 2);
  const int a_col = (lane & 3) * 8;                 // 8 bf16 = 16B
  const u16* gA = h + (brow + a_row)*1024 + a_col;
  u16* lA = &ldsA[wave*512];                        // +q*2048 elems

  // B staging: 4 issues; issue q covers rows q*32 + wave*8 + lane/8
  const int b_row = wave*8 + (lane >> 3);
  const int b_col = (lane & 7) * 4;                 // 4 f32 = 16B
  const float* gB = W2 + (t0 + b_row)*1024 + b_col;
  float* lB = &ldsB[wave*256];                      // +q*1024 elems

  const int fr = lane & 15, fk = (lane >> 4) * 8;
  const u16*   rdA = &ldsA[(wm*64 + fr)*32 + fk];
  const float* rdB = &ldsB[(wn*64 + fr)*32 + fk];

  f32x4 acc[4][4] = {};
  for (int kt = 0; kt < 32; ++kt) {
    __syncthreads();
#pragma unroll
    for (int q = 0; q < 2; ++q)
      gload_lds16(gA + q*64*1024 + kt*32, lA + q*2048);
#pragma unroll
    for (int q = 0; q < 4; ++q)
      gload_lds16(gB + q*32*1024 + kt*32, lB + q*1024);
    __syncthreads();

    bf16x8 af[4];
#pragma unroll
    for (int m = 0; m < 4; ++m)
      af[m] = *(const bf16x8*)(rdA + m*512);
#pragma unroll
    for (int n = 0; n < 4; ++n) {
      f32x4 lo = *(const f32x4*)(rdB + n*512);
      f32x4 hi = *(const f32x4*)(rdB + n*512 + 4);
      u32x4 p = { pack2bf(lo.x,lo.y), pack2bf(lo.z,lo.w),
                  pack2bf(hi.x,hi.y), pack2bf(hi.z,hi.w) };
      bf16x8 bfr = __builtin_bit_cast(bf16x8, p);
#pragma unroll
      for (int m = 0; m < 4; ++m)
        acc[m][n] = __builtin_amdgcn_mfma_f32_16x16x32_bf16(af[m], bfr, acc[m][n], 0,0,0);
    }
  }

  // epilogue: t -> (i,j) strict-lower scatter, forward half only.
  // t depends only on n and lane&15 -> 4 index computations per thread.
#pragma unroll
  for (int n = 0; n < 4; ++n) {
    const int t = t0 + wn*64 + n*16 + fr;
    const float bias = b2[t];
    int i = (int)((1.0f + sqrtf((float)(8*t + 1))) * 0.5f);
    while (i*(i+1)/2 <= t) ++i;      // fixup (<=1 iter, f32 sqrt is near-exact)
    while (i*(i-1)/2 > t) --i;
    const int j = t - i*(i-1)/2;
    const int ijbase = i*256 + j;
#pragma unroll
    for (int m = 0; m < 4; ++m) {
      const int row0 = brow + wm*64 + m*16 + (lane >> 4)*4;
#pragma unroll
      for (int r = 0; r < 4; ++r)
        out[(size_t)(row0 + r)*65536 + ijbase] = acc[m][n][r] + bias;
    }
  }
}

// ---------------------------------------------------------------------------
// K3: antisymmetrize. Read lower 64x64 tiles, write -tile^T to upper; zero diag.
// LDS transpose with +1 padding (2-way bank alias only = free).
// grid = (10 tile-pairs, 1024 batches)
// ---------------------------------------------------------------------------
__global__ __launch_bounds__(256)
void k3_mirror(float* __restrict__ out)
{
  __shared__ float tile[64][65];
  const int b = blockIdx.y;
  const int k = blockIdx.x;
  int ib, jb;
  if (k < 4) { ib = k; jb = k; }
  else {
    const int pi[6] = {1,2,2,3,3,3};
    const int pj[6] = {0,0,1,0,1,2};
    ib = pi[k-4]; jb = pj[k-4];
  }
  const int i0 = ib*64, j0 = jb*64;
  float* A = out + (size_t)b*65536;
  const int tid = threadIdx.x;
  const int r = tid >> 2, c0 = (tid & 3) * 16;
#pragma unroll
  for (int q = 0; q < 4; ++q) {
    const float4 v = *(const float4*)(A + (i0 + r)*256 + j0 + c0 + q*4);
    tile[r][c0+q*4+0] = v.x;
    tile[r][c0+q*4+1] = v.y;
    tile[r][c0+q*4+2] = v.z;
    tile[r][c0+q*4+3] = v.w;
  }
  __syncthreads();
  if (ib != jb) {
#pragma unroll
    for (int q = 0; q < 4; ++q) {
      const int c = c0 + q*4;
      float4 v;
      v.x = -tile[c+0][r]; v.y = -tile[c+1][r];
      v.z = -tile[c+2][r]; v.w = -tile[c+3][r];
      *(float4*)(A + (j0 + r)*256 + i0 + c) = v;
    }
  } else {
    // diagonal block: only fill strict upper + diag; leave lower intact
#pragma unroll
    for (int q = 0; q < 16; ++q) {
      const int c = c0 + q;
      if (c > r)       A[(j0 + r)*256 + i0 + c] = -tile[c][r];
      else if (c == r) A[(j0 + r)*256 + i0 + c] = 0.f;
    }
  }
}

// ---------------------------------------------------------------------------
extern "C" void kernel_launch(void* const* d_in, const int* in_sizes, int n_in,
                              void* d_out, int out_size, void* d_ws, size_t ws_size,
                              hipStream_t stream) {
  const float* x  = (const float*)d_in[0];
  const float* W1 = (const float*)d_in[1];
  const float* b1 = (const float*)d_in[2];
  const float* W2 = (const float*)d_in[3];
  const float* b2 = (const float*)d_in[4];
  float* out = (float*)d_out;
  u16* h = (u16*)d_ws;   // 1024*1024 bf16 = 2 MB scratch

  k1_gemm_softplus<<<dim3(64),        dim3(256), 0, stream>>>(x, W1, b1, h);
  k2_gemm_scatter <<<dim3(2040),      dim3(256), 0, stream>>>(h, W2, b2, out);
  k3_mirror       <<<dim3(10, 1024),  dim3(256), 0, stream>>>(out);
}

// Round 2
// 258.317 us; speedup vs baseline: 1.1882x; 1.1882x over previous
//
#include <hip/hip_runtime.h>
#include <cstdint>
#include <cstddef>

// Problem constants
//   x[1024,256] f32, W1[1024,256] f32, b1[1024], W2[32896,1024] f32, b2[32896]
//   h = softplus(x@W1^T + b1)          [1024,1024]  (kept bf16 in ws)
//   elements = h@W2^T + b2             first TRI=32640 cols used
//   out[b,i,j] = elements[b, i(i-1)/2+j] for i>j; out[b,j,i] = -that; diag 0
#define TRI 32640

using u32   = unsigned int;
using u16   = unsigned short;
using f32x4 = __attribute__((ext_vector_type(4))) float;
using u32x4 = __attribute__((ext_vector_type(4))) u32;
using bf16x8 = __attribute__((ext_vector_type(8))) short;   // 8 bf16 (guide §3)

__device__ __forceinline__ void gload_lds16(const void* g, void* l) {
  // async global->LDS, 16B/lane; LDS dest = wave-uniform base + lane*16
  __builtin_amdgcn_global_load_lds(
      (const __attribute__((address_space(1))) void*)g,
      (__attribute__((address_space(3))) void*)l, 16, 0, 0);
}

// truncating f32 pair -> packed bf16x2
__device__ __forceinline__ u32 pack2bf(float a, float b) {
  u32 ua = __builtin_bit_cast(u32, a);
  u32 ub = __builtin_bit_cast(u32, b);
  return (ub & 0xffff0000u) | (ua >> 16);
}

__device__ __forceinline__ u16 f2bf_rn(float f) {  // round-to-nearest-even
  u32 u = __builtin_bit_cast(u32, f);
  u += 0x7fffu + ((u >> 16) & 1u);
  return (u16)(u >> 16);
}

// ---------------------------------------------------------------------------
// K0 (fused): blocks 0-63   : h = softplus(x @ W1^T + b1), bf16 out (m97-style)
//             blocks 64-1087: convert W2[0:TRI,:] f32 -> bf16(rn) into ws
// The GEMM only fills 64 CUs; the conversion streams on the rest concurrently.
// ---------------------------------------------------------------------------
__global__ __launch_bounds__(256)
void k0_fused(const float* __restrict__ x, const float* __restrict__ W1,
              const float* __restrict__ b1, u16* __restrict__ h,
              const float* __restrict__ W2, u16* __restrict__ W2b)
{
  __shared__ float ldsA[128*32];   // 16 KB
  __shared__ float ldsB[128*32];   // 16 KB

  if (blockIdx.x >= 64) {
    // ---- W2 -> bf16 conversion, grid-stride float4 ----
    const int g0 = (blockIdx.x - 64)*256 + threadIdx.x;
    const f32x4* src = (const f32x4*)W2;
    const int n4 = TRI*1024/4;            // 8,355,840 (exact)
    for (int v = g0; v < n4; v += 1024*256) {
      f32x4 f = src[v];
      uint2 p;
      p.x = (u32)f2bf_rn(f.x) | ((u32)f2bf_rn(f.y) << 16);
      p.y = (u32)f2bf_rn(f.z) | ((u32)f2bf_rn(f.w) << 16);
      *(uint2*)(W2b + (size_t)v*4) = p;
    }
    return;
  }

  // ---- GEMM1 + softplus (unchanged from round 1, passed) ----
  const int tid = threadIdx.x, lane = tid & 63, wave = tid >> 6;
  const int wm = wave >> 1, wn = wave & 1;
  const int brow = (blockIdx.x & 7) * 128, bcol = (blockIdx.x >> 3) * 128;

  const int s_row = wave*8 + (lane >> 3);
  const int s_col = (lane & 7) * 4;                 // 4 f32 = 16B
  const float* gA = x  + (brow + s_row)*256 + s_col;
  const float* gB = W1 + (bcol + s_row)*256 + s_col;
  float* lA = &ldsA[wave*256];
  float* lB = &ldsB[wave*256];

  const int fr = lane & 15, fk = (lane >> 4) * 8;
  const float* rdA = &ldsA[(wm*64 + fr)*32 + fk];
  const float* rdB = &ldsB[(wn*64 + fr)*32 + fk];

  f32x4 acc[4][4] = {};
  for (int kt = 0; kt < 8; ++kt) {
    __syncthreads();
#pragma unroll
    for (int q = 0; q < 4; ++q) {
      gload_lds16(gA + q*32*256 + kt*32, lA + q*1024);
      gload_lds16(gB + q*32*256 + kt*32, lB + q*1024);
    }
    __syncthreads();
    bf16x8 af[4], bfv[4];
#pragma unroll
    for (int m = 0; m < 4; ++m) {
      f32x4 lo = *(const f32x4*)(rdA + m*512);
      f32x4 hi = *(const f32x4*)(rdA + m*512 + 4);
      u32x4 p = { pack2bf(lo.x,lo.y), pack2bf(lo.z,lo.w),
                  pack2bf(hi.x,hi.y), pack2bf(hi.z,hi.w) };
      af[m] = __builtin_bit_cast(bf16x8, p);
    }
#pragma unroll
    for (int n = 0; n < 4; ++n) {
      f32x4 lo = *(const f32x4*)(rdB + n*512);
      f32x4 hi = *(const f32x4*)(rdB + n*512 + 4);
      u32x4 p = { pack2bf(lo.x,lo.y), pack2bf(lo.z,lo.w),
                  pack2bf(hi.x,hi.y), pack2bf(hi.z,hi.w) };
      bfv[n] = __builtin_bit_cast(bf16x8, p);
    }
#pragma unroll
    for (int m = 0; m < 4; ++m)
#pragma unroll
      for (int n = 0; n < 4; ++n)
        acc[m][n] = __builtin_amdgcn_mfma_f32_16x16x32_bf16(af[m], bfv[n], acc[m][n], 0,0,0);
  }
#pragma unroll
  for (int n = 0; n < 4; ++n) {
    const int col = bcol + wn*64 + n*16 + fr;
    const float bias = b1[col];
#pragma unroll
    for (int m = 0; m < 4; ++m) {
      const int row0 = brow + wm*64 + m*16 + (lane >> 4)*4;
#pragma unroll
      for (int r = 0; r < 4; ++r) {
        float z = acc[m][n][r] + bias;
        float sp = fmaxf(z, 0.f) + log1pf(expf(-fabsf(z)));   // stable softplus
        h[(row0 + r)*1024 + col] = f2bf_rn(sp);
      }
    }
  }
}

// ---------------------------------------------------------------------------
// K2 (fast path): elements = h @ W2b^T (+b2) with both operands bf16.
// Exact m97 clone: 128x128 tile, BK=32, 4 waves, 2 gload_lds issues/operand.
// M=1024 (batch), N=32640 (tri index), K=1024. 255x8 = 2040 blocks.
// Forward (lower-triangle, j-contiguous) write only; mirror by K3.
// ---------------------------------------------------------------------------
__global__ __launch_bounds__(256)
void k2_gemm_scatter_bf(const u16* __restrict__ h, const u16* __restrict__ W2b,
                        const float* __restrict__ b2, float* __restrict__ out)
{
  __shared__ u16 ldsA[128*32];   // 8 KB
  __shared__ u16 ldsB[128*32];   // 8 KB
  const int tid = threadIdx.x, lane = tid & 63, wave = tid >> 6;
  const int wm = wave >> 1, wn = wave & 1;

  // XCD-bijective swizzle (2040 % 8 == 0): 8 batch-blocks sharing a W2 panel
  // land on one XCD's L2.
  const int bid = blockIdx.x;
  const int L  = (bid & 7) * 255 + (bid >> 3);
  const int t0 = (L >> 3) * 128;          // t-tile base (0..32512)
  const int brow = (L & 7) * 128;         // batch-tile base

  // staging: 2 issues/operand; issue q covers rows q*64 + wave*16 + lane/4
  const int s_row = wave*16 + (lane >> 2);
  const int s_col = (lane & 3) * 8;                 // 8 bf16 = 16B
  const u16* gA = h   + (brow + s_row)*1024 + s_col;
  const u16* gB = W2b + (size_t)(t0 + s_row)*1024 + s_col;
  u16* lA = &ldsA[wave*512];                        // +q*2048 elems
  u16* lB = &ldsB[wave*512];

  const int fr = lane & 15, fk = (lane >> 4) * 8;
  const u16* rdA = &ldsA[(wm*64 + fr)*32 + fk];
  const u16* rdB = &ldsB[(wn*64 + fr)*32 + fk];

  f32x4 acc[4][4] = {};
  for (int kt = 0; kt < 32; ++kt) {
    __syncthreads();
    gload_lds16(gA +           kt*32, lA);
    gload_lds16(gA + 64*1024 + kt*32, lA + 2048);
    gload_lds16(gB +           kt*32, lB);
    gload_lds16(gB + 64*1024 + kt*32, lB + 2048);
    __syncthreads();

    bf16x8 af[4], bfv[4];
#pragma unroll
    for (int m = 0; m < 4; ++m)
      af[m] = *(const bf16x8*)(rdA + m*512);
#pragma unroll
    for (int n = 0; n < 4; ++n)
      bfv[n] = *(const bf16x8*)(rdB + n*512);
#pragma unroll
    for (int m = 0; m < 4; ++m)
#pragma unroll
      for (int n = 0; n < 4; ++n)
        acc[m][n] = __builtin_amdgcn_mfma_f32_16x16x32_bf16(af[m], bfv[n], acc[m][n], 0,0,0);
  }

  // epilogue: t -> (i,j) strict-lower scatter, forward half only.
#pragma unroll
  for (int n = 0; n < 4; ++n) {
    const int t = t0 + wn*64 + n*16 + fr;
    const float bias = b2[t];
    int i = (int)((1.0f + sqrtf((float)(8*t + 1))) * 0.5f);
    while (i*(i+1)/2 <= t) ++i;
    while (i*(i-1)/2 > t) --i;
    const int j = t - i*(i-1)/2;
    const int ijbase = i*256 + j;
#pragma unroll
    for (int m = 0; m < 4; ++m) {
      const int row0 = brow + wm*64 + m*16 + (lane >> 4)*4;
#pragma unroll
      for (int r = 0; r < 4; ++r)
        out[(size_t)(row0 + r)*65536 + ijbase] = acc[m][n][r] + bias;
    }
  }
}

// ---------------------------------------------------------------------------
// K2 (fallback path, round-1 version): W2 staged f32, packed at frag load.
// Used only when ws_size is too small for the bf16-converted W2.
// ---------------------------------------------------------------------------
__global__ __launch_bounds__(256)
void k2_gemm_scatter(const u16* __restrict__ h, const float* __restrict__ W2,
                     const float* __restrict__ b2, float* __restrict__ out)
{
  __shared__ u16   ldsA[128*32];
  __shared__ float ldsB[128*32];
  const int tid = threadIdx.x, lane = tid & 63, wave = tid >> 6;
  const int wm = wave >> 1, wn = wave & 1;
  const int bid = blockIdx.x;
  const int L  = (bid & 7) * 255 + (bid >> 3);
  const int t0 = (L >> 3) * 128;
  const int brow = (L & 7) * 128;

  const int a_row = wave*16 + (lane >> 2);
  const int a_col = (lane & 3) * 8;
  const u16* gA = h + (brow + a_row)*1024 + a_col;
  u16* lA = &ldsA[wave*512];

  const int b_row = wave*8 + (lane >> 3);
  const int b_col = (lane & 7) * 4;
  const float* gB = W2 + (size_t)(t0 + b_row)*1024 + b_col;
  float* lB = &ldsB[wave*256];

  const int fr = lane & 15, fk = (lane >> 4) * 8;
  const u16*   rdA = &ldsA[(wm*64 + fr)*32 + fk];
  const float* rdB = &ldsB[(wn*64 + fr)*32 + fk];

  f32x4 acc[4][4] = {};
  for (int kt = 0; kt < 32; ++kt) {
    __syncthreads();
#pragma unroll
    for (int q = 0; q < 2; ++q)
      gload_lds16(gA + q*64*1024 + kt*32, lA + q*2048);
#pragma unroll
    for (int q = 0; q < 4; ++q)
      gload_lds16(gB + q*32*1024 + kt*32, lB + q*1024);
    __syncthreads();

    bf16x8 af[4];
#pragma unroll
    for (int m = 0; m < 4; ++m)
      af[m] = *(const bf16x8*)(rdA + m*512);
#pragma unroll
    for (int n = 0; n < 4; ++n) {
      f32x4 lo = *(const f32x4*)(rdB + n*512);
      f32x4 hi = *(const f32x4*)(rdB + n*512 + 4);
      u32x4 p = { pack2bf(lo.x,lo.y), pack2bf(lo.z,lo.w),
                  pack2bf(hi.x,hi.y), pack2bf(hi.z,hi.w) };
      bf16x8 bfr = __builtin_bit_cast(bf16x8, p);
#pragma unroll
      for (int m = 0; m < 4; ++m)
        acc[m][n] = __builtin_amdgcn_mfma_f32_16x16x32_bf16(af[m], bfr, acc[m][n], 0,0,0);
    }
  }
#pragma unroll
  for (int n = 0; n < 4; ++n) {
    const int t = t0 + wn*64 + n*16 + fr;
    const float bias = b2[t];
    int i = (int)((1.0f + sqrtf((float)(8*t + 1))) * 0.5f);
    while (i*(i+1)/2 <= t) ++i;
    while (i*(i-1)/2 > t) --i;
    const int j = t - i*(i-1)/2;
    const int ijbase = i*256 + j;
#pragma unroll
    for (int m = 0; m < 4; ++m) {
      const int row0 = brow + wm*64 + m*16 + (lane >> 4)*4;
#pragma unroll
      for (int r = 0; r < 4; ++r)
        out[(size_t)(row0 + r)*65536 + ijbase] = acc[m][n][r] + bias;
    }
  }
}

// ---------------------------------------------------------------------------
// K1 (fallback path only)
// ---------------------------------------------------------------------------
__global__ __launch_bounds__(256)
void k1_gemm_softplus(const float* __restrict__ x, const float* __restrict__ W1,
                      const float* __restrict__ b1, u16* __restrict__ h)
{
  __shared__ float ldsA[128*32];
  __shared__ float ldsB[128*32];
  const int tid = threadIdx.x, lane = tid & 63, wave = tid >> 6;
  const int wm = wave >> 1, wn = wave & 1;
  const int brow = (blockIdx.x & 7) * 128, bcol = (blockIdx.x >> 3) * 128;

  const int s_row = wave*8 + (lane >> 3);
  const int s_col = (lane & 7) * 4;
  const float* gA = x  + (brow + s_row)*256 + s_col;
  const float* gB = W1 + (bcol + s_row)*256 + s_col;
  float* lA = &ldsA[wave*256];
  float* lB = &ldsB[wave*256];

  const int fr = lane & 15, fk = (lane >> 4) * 8;
  const float* rdA = &ldsA[(wm*64 + fr)*32 + fk];
  const float* rdB = &ldsB[(wn*64 + fr)*32 + fk];

  f32x4 acc[4][4] = {};
  for (int kt = 0; kt < 8; ++kt) {
    __syncthreads();
#pragma unroll
    for (int q = 0; q < 4; ++q) {
      gload_lds16(gA + q*32*256 + kt*32, lA + q*1024);
      gload_lds16(gB + q*32*256 + kt*32, lB + q*1024);
    }
    __syncthreads();
    bf16x8 af[4], bfv[4];
#pragma unroll
    for (int m = 0; m < 4; ++m) {
      f32x4 lo = *(const f32x4*)(rdA + m*512);
      f32x4 hi = *(const f32x4*)(rdA + m*512 + 4);
      u32x4 p = { pack2bf(lo.x,lo.y), pack2bf(lo.z,lo.w),
                  pack2bf(hi.x,hi.y), pack2bf(hi.z,hi.w) };
      af[m] = __builtin_bit_cast(bf16x8, p);
    }
#pragma unroll
    for (int n = 0; n < 4; ++n) {
      f32x4 lo = *(const f32x4*)(rdB + n*512);
      f32x4 hi = *(const f32x4*)(rdB + n*512 + 4);
      u32x4 p = { pack2bf(lo.x,lo.y), pack2bf(lo.z,lo.w),
                  pack2bf(hi.x,hi.y), pack2bf(hi.z,hi.w) };
      bfv[n] = __builtin_bit_cast(bf16x8, p);
    }
#pragma unroll
    for (int m = 0; m < 4; ++m)
#pragma unroll
      for (int n = 0; n < 4; ++n)
        acc[m][n] = __builtin_amdgcn_mfma_f32_16x16x32_bf16(af[m], bfv[n], acc[m][n], 0,0,0);
  }
#pragma unroll
  for (int n = 0; n < 4; ++n) {
    const int col = bcol + wn*64 + n*16 + fr;
    const float bias = b1[col];
#pragma unroll
    for (int m = 0; m < 4; ++m) {
      const int row0 = brow + wm*64 + m*16 + (lane >> 4)*4;
#pragma unroll
      for (int r = 0; r < 4; ++r) {
        float z = acc[m][n][r] + bias;
        float sp = fmaxf(z, 0.f) + log1pf(expf(-fabsf(z)));
        h[(row0 + r)*1024 + col] = f2bf_rn(sp);
      }
    }
  }
}

// ---------------------------------------------------------------------------
// K3: antisymmetrize. Read lower 64x64 tiles, write -tile^T to upper.
// Diagonal tiles now write FULL rows (lower rewritten with identical values,
// diag 0, upper = -transpose) -> full-line stores, no partial-line RMW.
// grid = (10 tile-pairs, 1024 batches)
// ---------------------------------------------------------------------------
__global__ __launch_bounds__(256)
void k3_mirror(float* __restrict__ out)
{
  __shared__ float tile[64][65];
  const int b = blockIdx.y;
  const int k = blockIdx.x;
  int ib, jb;
  if (k < 4) { ib = k; jb = k; }
  else {
    const int pi[6] = {1,2,2,3,3,3};
    const int pj[6] = {0,0,1,0,1,2};
    ib = pi[k-4]; jb = pj[k-4];
  }
  const int i0 = ib*64, j0 = jb*64;
  float* A = out + (size_t)b*65536;
  const int tid = threadIdx.x;
  const int r = tid >> 2, c0 = (tid & 3) * 16;
#pragma unroll
  for (int q = 0; q < 4; ++q) {
    const float4 v = *(const float4*)(A + (i0 + r)*256 + j0 + c0 + q*4);
    tile[r][c0+q*4+0] = v.x;
    tile[r][c0+q*4+1] = v.y;
    tile[r][c0+q*4+2] = v.z;
    tile[r][c0+q*4+3] = v.w;
  }
  __syncthreads();
  if (ib != jb) {
#pragma unroll
    for (int q = 0; q < 4; ++q) {
      const int c = c0 + q*4;
      float4 v;
      v.x = -tile[c+0][r]; v.y = -tile[c+1][r];
      v.z = -tile[c+2][r]; v.w = -tile[c+3][r];
      *(float4*)(A + (j0 + r)*256 + i0 + c) = v;
    }
  } else {
    // diagonal block: full rows, branch-free per element, full-line stores
#pragma unroll
    for (int q = 0; q < 4; ++q) {
      const int cb = c0 + q*4;
      float4 v;
#pragma unroll
      for (int e = 0; e < 4; ++e) {
        const int c = cb + e;
        float val = (c < r) ? tile[r][c] : ((c == r) ? 0.f : -tile[c][r]);
        ((float*)&v)[e] = val;
      }
      *(float4*)(A + (i0 + r)*256 + j0 + cb) = v;
    }
  }
}

// ---------------------------------------------------------------------------
extern "C" void kernel_launch(void* const* d_in, const int* in_sizes, int n_in,
                              void* d_out, int out_size, void* d_ws, size_t ws_size,
                              hipStream_t stream) {
  const float* x  = (const float*)d_in[0];
  const float* W1 = (const float*)d_in[1];
  const float* b1 = (const float*)d_in[2];
  const float* W2 = (const float*)d_in[3];
  const float* b2 = (const float*)d_in[4];
  float* out = (float*)d_out;
  u16* h = (u16*)d_ws;                               // 2 MB

  const size_t need = 2u*1024*1024 + (size_t)TRI*1024*2;   // h + W2 bf16
  if (ws_size >= need) {
    u16* W2b = (u16*)((char*)d_ws + 2u*1024*1024);
    k0_fused          <<<dim3(64 + 1024), dim3(256), 0, stream>>>(x, W1, b1, h, W2, W2b);
    k2_gemm_scatter_bf<<<dim3(2040),      dim3(256), 0, stream>>>(h, W2b, b2, out);
  } else {
    k1_gemm_softplus  <<<dim3(64),        dim3(256), 0, stream>>>(x, W1, b1, h);
    k2_gemm_scatter   <<<dim3(2040),      dim3(256), 0, stream>>>(h, W2, b2, out);
  }
  k3_mirror           <<<dim3(10, 1024),  dim3(256), 0, stream>>>(out);
}